// Round 4
// baseline (298.670 us; speedup 1.0000x reference)
//
#include <hip/hip_runtime.h>
#include <cstdint>

#define BB 256
#define DD 512
#define CC 345
#define NBANK 50000
#define NPAD 50048          // 782 * 64
#define KNEI 5
#define ALPHAC 1.0f
#define EPSN 1e-12f
#define NHALF 782           // 64-col tiles
#define CSLOTS (NHALF * 2)  // 2 keys per tile -> 1564 u64 per row

typedef short short8 __attribute__((ext_vector_type(8)));
typedef float f32x4 __attribute__((ext_vector_type(4)));
typedef unsigned long long u64;

__device__ inline uint32_t f2bf1(float x) {
    union { float f; uint32_t u; } v; v.f = x;
    return (v.u + 0x7FFFu + ((v.u >> 16) & 1u)) >> 16;
}
__device__ inline uint32_t pack2(float a, float b) {
    return f2bf1(a) | (f2bf1(b) << 16);
}
__device__ inline float bl(uint32_t x) {
    union { uint32_t u; float f; } v; v.u = x << 16; return v.f;
}
__device__ inline float bh(uint32_t x) {
    union { uint32_t u; float f; } v; v.u = x & 0xFFFF0000u; return v.f;
}
// packed sort key: high32 = monotone float bits, low32 = ~j (bigger = better)
__device__ inline u64 mkkey(float v, int j) {
    union { float f; uint32_t u; } c; c.f = v;
    uint32_t b = c.u;
    uint32_t k = (b & 0x80000000u) ? ~b : (b | 0x80000000u);
    return ((u64)k << 32) | (uint32_t)(~j);
}
__device__ inline u64 umax64(u64 a, u64 b) { return a > b ? a : b; }
__device__ inline u64 shfl_xor_u64(u64 v, int m) {
    int lo = __shfl_xor((int)(uint32_t)v, m, 64);
    int hi = __shfl_xor((int)(v >> 32), m, 64);
    return ((u64)(uint32_t)hi << 32) | (uint32_t)lo;
}
__device__ inline void ins6u(u64 k, u64* lv) {
    if (k > lv[5]) {
        int q = 5;
        while (q > 0 && k > lv[q - 1]) { lv[q] = lv[q - 1]; q--; }
        lv[q] = k;
    }
}
// 256-thread LDS tree merge of per-thread sorted-desc 6-tuples -> sv[0..5]
__device__ inline void tree6u(u64* sv, int t, const u64* lv) {
#pragma unroll
    for (int r = 0; r < 6; r++) sv[t * 6 + r] = lv[r];
    __syncthreads();
    for (int s = 128; s > 0; s >>= 1) {
        if (t < s) {
            u64 av[6], bv[6], rv[6];
#pragma unroll
            for (int r = 0; r < 6; r++) { av[r] = sv[t * 6 + r]; bv[r] = sv[(t + s) * 6 + r]; }
            int x = 0, y = 0;
#pragma unroll
            for (int o = 0; o < 6; o++) {
                bool pk = av[x] > bv[y];
                rv[o] = pk ? av[x] : bv[y];
                x += pk; y += !pk;
            }
#pragma unroll
            for (int r = 0; r < 6; r++) sv[t * 6 + r] = rv[r];
        }
        __syncthreads();
    }
}

// Kernel 1: fused row L2-normalize (-> fnb bf16) + row softmax + repl init
__global__ void norm_softmax_kernel(const float* __restrict__ feat,
                                    const float* __restrict__ pred,
                                    unsigned short* __restrict__ fnb,
                                    float* __restrict__ p,
                                    int* __restrict__ repl) {
    int b = blockIdx.x, t = threadIdx.x;
    // fused repl init: 256 blocks x 256 threads = 65536 >= NPAD
    int gi = b * 256 + t;
    if (gi < NPAD) repl[gi] = -1;
    __shared__ float red[256];
    float x0 = feat[b * DD + t];
    float x1 = feat[b * DD + t + 256];
    red[t] = x0 * x0 + x1 * x1;
    __syncthreads();
    for (int s = 128; s > 0; s >>= 1) {
        if (t < s) red[t] += red[t + s];
        __syncthreads();
    }
    float inv = 1.0f / fmaxf(sqrtf(red[0]), EPSN);
    if (t < 64) {
        const f32x4* src = (const f32x4*)(feat + b * DD + t * 8);
        f32x4 f0 = src[0], f1 = src[1];
        uint4 u = make_uint4(pack2(f0[0] * inv, f0[1] * inv),
                             pack2(f0[2] * inv, f0[3] * inv),
                             pack2(f1[0] * inv, f1[1] * inv),
                             pack2(f1[2] * inv, f1[3] * inv));
        *(uint4*)(fnb + b * DD + t * 8) = u;
    }
    __syncthreads();
    float y0 = (t < CC) ? pred[b * CC + t] : -3.0e38f;
    float y1 = (t + 256 < CC) ? pred[b * CC + t + 256] : -3.0e38f;
    red[t] = fmaxf(y0, y1);
    __syncthreads();
    for (int s = 128; s > 0; s >>= 1) {
        if (t < s) red[t] = fmaxf(red[t], red[t + s]);
        __syncthreads();
    }
    float M = red[0];
    __syncthreads();
    float e0 = (t < CC) ? expf(y0 - M) : 0.f;
    float e1 = (t + 256 < CC) ? expf(y1 - M) : 0.f;
    red[t] = e0 + e1;
    __syncthreads();
    for (int s = 128; s > 0; s >>= 1) {
        if (t < s) red[t] += red[t + s];
        __syncthreads();
    }
    float si = 1.0f / red[0];
    if (t < CC) p[b * CC + t] = e0 * si;
    if (t + 256 < CC) p[b * CC + t + 256] = e1 * si;
}

// Kernel 2: zero out; last-write-wins scatter repl[trg[b]] = b
__global__ void winner_kernel(const int* __restrict__ trg, int* __restrict__ repl,
                              float* __restrict__ out) {
    int t = threadIdx.x;
    __shared__ int st[BB];
    if (t == 0) out[0] = 0.f;
    st[t] = trg[t];
    __syncthreads();
    int mv = st[t];
    int w = 1;
    for (int b2 = t + 1; b2 < BB; b2++)
        if (st[b2] == mv) w = 0;
    if (w) repl[mv] = t;
}

// Kernel 3: 256x64x512 bf16 MFMA GEMM, v4 one-shot staging.
//   - grid 782 (one block per 64-col bank tile), 4 waves, 256 A-rows/block
//     -> bank is read exactly ONCE (no row-half duplication).
//   - whole 64x512 B panel staged to LDS in one pass (64 KB, XOR-swizzled,
//     wave-uniform repl patch via lane-table + shfl) -> ONE vmcnt(0)+barrier
//     drain per block instead of 8 (R2 showed the 8 serial drains, not BW,
//     were the cost: dur tracked latency at 22% HBM).
//   - A fragments read directly from global fnb (256 KB, L2-resident,
//     pipelined under the fully unrolled 128-MFMA loop); fnb2 eliminated.
__global__ __launch_bounds__(256) void gemm_topk_kernel(
        const unsigned short* __restrict__ fnb, const float* __restrict__ bank,
        const int* __restrict__ repl, u64* __restrict__ cand) {
    __shared__ __align__(16) char smem[65536];   // B panel [64 rows][512 cols] bf16

    int t = threadIdx.x;
    int ntb = blockIdx.x;          // 0..781 col tile
    int j0 = ntb * 64;
    int w = t >> 6, lane = t & 63, quad = lane >> 4, l16 = lane & 15;

    // repl for this tile's 64 rows, one per lane (wave-uniform broadcast later)
    int rpv = (j0 + lane < NBANK) ? repl[j0 + lane] : -2;

    const char* bankb = (const char*)bank;
    const char* fnbb = (const char*)fnb;

    // ---- one-shot B staging: 16 iters, wave w handles row i*4+w per iter ----
#pragma unroll 4
    for (int i = 0; i < 16; i++) {
        int r = i * 4 + w;
        int rp = __shfl(rpv, r);               // wave-uniform
        uint4 u = make_uint4(0u, 0u, 0u, 0u);
        if (rp >= 0) {
            u = *(const uint4*)(fnbb + (size_t)rp * 1024 + lane * 16);
        } else if (rp == -1) {
            const f32x4* s = (const f32x4*)(bankb + (size_t)(j0 + r) * 2048 + lane * 32);
            f32x4 a = s[0], b2 = s[1];
            u = make_uint4(pack2(a[0], a[1]), pack2(a[2], a[3]),
                           pack2(b2[0], b2[1]), pack2(b2[2], b2[3]));
        }
        int slot = lane ^ (r & 7);             // 16B-chunk XOR swizzle
        *(uint4*)(smem + (size_t)r * 1024 + slot * 16) = u;
    }
    __syncthreads();   // the ONLY drain in this kernel

    // ---- compute: 8 kt x 2 ks, A from global (L2), B from LDS ----
    f32x4 acc[4][4];
#pragma unroll
    for (int mt = 0; mt < 4; mt++)
#pragma unroll
        for (int nt = 0; nt < 4; nt++)
            acc[mt][nt] = (f32x4){0.f, 0.f, 0.f, 0.f};

#pragma unroll
    for (int kt = 0; kt < 8; kt++) {
#pragma unroll
        for (int ks = 0; ks < 2; ks++) {
            int c = kt * 8 + ks * 4 + quad;            // 16B chunk 0..63
            int sw = (c ^ (l16 & 7)) * 16;             // swizzled byte offset
            short8 af[4], bf[4];
#pragma unroll
            for (int mt = 0; mt < 4; mt++)
                af[mt] = *(const short8*)(fnbb +
                    (size_t)(w * 64 + mt * 16 + l16) * 1024 + c * 16);
#pragma unroll
            for (int nt = 0; nt < 4; nt++)
                bf[nt] = *(const short8*)(smem + (size_t)(nt * 16 + l16) * 1024 + sw);
#pragma unroll
            for (int mt = 0; mt < 4; mt++)
#pragma unroll
                for (int nt = 0; nt < 4; nt++)
                    acc[mt][nt] = __builtin_amdgcn_mfma_f32_16x16x32_bf16(
                        af[mt], bf[nt], acc[mt][nt], 0, 0, 0);
        }
    }

    // ---- branchless epilogue: top-2 packed keys per (row, 64 cols) ----
    bool maskPad[4];
#pragma unroll
    for (int nt = 0; nt < 4; nt++)
        maskPad[nt] = (ntb == NHALF - 1) && ((j0 + nt * 16 + l16) >= NBANK);

#pragma unroll
    for (int mt = 0; mt < 4; mt++)
#pragma unroll
        for (int r2 = 0; r2 < 4; r2++) {
            u64 k[4];
#pragma unroll
            for (int nt = 0; nt < 4; nt++) {
                int j = j0 + nt * 16 + l16;
                k[nt] = maskPad[nt] ? 0ull : mkkey(acc[mt][nt][r2], j);
            }
            u64 m = umax64(umax64(k[0], k[1]), umax64(k[2], k[3]));
#pragma unroll
            for (int off = 1; off < 16; off <<= 1)
                m = umax64(m, shfl_xor_u64(m, off));
            u64 top1 = m;
#pragma unroll
            for (int nt = 0; nt < 4; nt++) k[nt] = (k[nt] == top1) ? 0ull : k[nt];
            m = umax64(umax64(k[0], k[1]), umax64(k[2], k[3]));
#pragma unroll
            for (int off = 1; off < 16; off <<= 1)
                m = umax64(m, shfl_xor_u64(m, off));
            if (l16 == 0) {
                int gi = w * 64 + mt * 16 + quad * 4 + r2;
                u64* cp = cand + (size_t)gi * CSLOTS + ntb * 2;
                cp[0] = top1; cp[1] = m;
            }
        }
}

// Kernel 4: fused merge + KL (blocks 0..255) and neg_pred (blocks 256..600).
// Merge row i's 1564 stored keys -> exact top-6 (rare fallback rescan), then
// immediately compute row i's KL term from the in-LDS neighbor list.
__global__ __launch_bounds__(256) void mergekl_kernel(
        const u64* __restrict__ cand, const unsigned short* __restrict__ fnb,
        const float* __restrict__ bank, const int* __restrict__ repl,
        const float* __restrict__ p, const float* __restrict__ sbank,
        const int* __restrict__ trg, float* __restrict__ out) {
    int bid = blockIdx.x, t = threadIdx.x;
    __shared__ float red[256];
    if (bid >= BB) {
        // ---- neg_pred column block ----
        __shared__ float aux[256];
        int c = bid - BB;
        float v = p[t * CC + c];
        red[t] = v;
        aux[t] = v * v;
        __syncthreads();
        for (int s = 128; s > 0; s >>= 1) {
            if (t < s) { red[t] += red[t + s]; aux[t] += aux[t + s]; }
            __syncthreads();
        }
        if (t == 0) atomicAdd(out, ALPHAC * (red[0] * red[0] - aux[0]) * (1.0f / BB));
        return;
    }
    // ---- merge part ----
    int i = bid;
    __shared__ u64 sv[1536];
    __shared__ uint32_t fm[25];
    __shared__ int fl[128];
    __shared__ int nf;
    __shared__ float a[512];
    const u64* cr = cand + (size_t)i * CSLOTS;

    u64 lv[6] = {0, 0, 0, 0, 0, 0};
    for (int q = t; q < CSLOTS; q += 256) ins6u(cr[q], lv);
    if (t < 25) fm[t] = 0;
    if (t == 0) nf = 0;
    tree6u(sv, t, lv);
    u64 M6 = sv[5];
    __syncthreads();
    for (int h = t; h < NHALF; h += 256) {
        if (cr[h * 2 + 1] >= M6) {
            int s = atomicAdd(&nf, 1);
            if (s < 128) fl[s] = h;
            atomicOr(&fm[h >> 5], 1u << (h & 31));
        }
    }
    __syncthreads();
    if (nf > 0) {   // exact fallback — rare
        uint32_t wrd = ((const uint32_t*)(fnb + (size_t)i * DD))[t];
        a[2 * t] = bl(wrd);
        a[2 * t + 1] = bh(wrd);
        __syncthreads();
        u64 l2[6] = {0, 0, 0, 0, 0, 0};
        for (int q = t; q < CSLOTS; q += 256) {    // stored keys, unflagged tiles
            int h = q >> 1;
            if (!((fm[h >> 5] >> (h & 31)) & 1u)) ins6u(cr[q], l2);
        }
        int nfl = nf < 128 ? nf : 128;
        for (int s = 0; s < nfl; s++) {            // full recompute, flagged tiles
            int h = fl[s];
            if (t < 64) {
                int j = h * 64 + t;
                if (j < NBANK) {
                    int rp = repl[j];
                    float dot = 0.f;
                    if (rp >= 0) {
                        const uint32_t* rw = (const uint32_t*)(fnb + (size_t)rp * DD);
                        for (int kk = 0; kk < 256; kk++) {
                            uint32_t u = rw[kk];
                            dot += bl(u) * a[2 * kk] + bh(u) * a[2 * kk + 1];
                        }
                    } else {
                        const float* rw = bank + (size_t)j * DD;
                        for (int kk = 0; kk < DD; kk++)
                            dot += bl(f2bf1(rw[kk])) * a[kk];
                    }
                    ins6u(mkkey(dot, j), l2);
                }
            }
        }
        __syncthreads();
        tree6u(sv, t, l2);
    }
    // ---- KL part: neighbors are sv[1..5] (rank 0 = self) ----
    __shared__ int st[BB];
    __shared__ int sj[KNEI], sb2[KNEI];
    st[t] = trg[t];
    if (t < KNEI) {
        sj[t] = (int)(~(uint32_t)(sv[t + 1] & 0xFFFFFFFFull));
        sb2[t] = -1;
    }
    __syncthreads();
    // last-write-wins source: highest b2 with trg[b2] == j
#pragma unroll
    for (int k = 0; k < KNEI; k++)
        if (st[t] == sj[k]) atomicMax(&sb2[k], t);
    __syncthreads();
    float local = 0.f;
    for (int k = 0; k < KNEI; k++) {
        int j = sj[k], src = sb2[k];
        const float* srow = (src >= 0) ? (p + src * CC) : (sbank + (size_t)j * CC);
        for (int c = t; c < CC; c += 256) {
            float s = srow[c];
            local += s * (logf(s) - p[i * CC + c]);
        }
    }
    red[t] = local;
    __syncthreads();
    for (int s = 128; s > 0; s >>= 1) {
        if (t < s) red[t] += red[t + s];
        __syncthreads();
    }
    if (t == 0) atomicAdd(out, red[0] * (1.0f / BB));
}

extern "C" void kernel_launch(void* const* d_in, const int* in_sizes, int n_in,
                              void* d_out, int out_size, void* d_ws, size_t ws_size,
                              hipStream_t stream) {
    const float* feat  = (const float*)d_in[0];
    const float* pred  = (const float*)d_in[1];
    const float* bank  = (const float*)d_in[2];
    const float* sbank = (const float*)d_in[3];
    const int*   trg   = (const int*)d_in[4];
    float* out = (float*)d_out;

    char* ws = (char*)d_ws;
    unsigned short* fnb  = (unsigned short*)ws;              //   262,144 B
    float*          p    = (float*)(ws + 262144);            //   353,280 B
    int*            repl = (int*)(ws + 615424);              //   200,192 B
    u64*            cand = (u64*)(ws + 815616);              // 3,203,072 B

    norm_softmax_kernel<<<BB, 256, 0, stream>>>(feat, pred, fnb, p, repl);
    winner_kernel<<<1, 256, 0, stream>>>(trg, repl, out);
    gemm_topk_kernel<<<NHALF, 256, 0, stream>>>(fnb, bank, repl, cand);
    mergekl_kernel<<<BB + CC, 256, 0, stream>>>(cand, fnb, bank, repl, p, sbank, trg, out);
}

// Round 6
// 270.473 us; speedup vs baseline: 1.1042x; 1.1042x over previous
//
#include <hip/hip_runtime.h>
#include <cstdint>

#define BB 256
#define DD 512
#define CC 345
#define NBANK 50000
#define NPAD 50048          // 782 * 64
#define KNEI 5
#define ALPHAC 1.0f
#define EPSN 1e-12f
#define NHALF 782           // 64-col tiles
#define CSLOTS (NHALF * 2)  // 2 keys per tile -> 1564 u64 per row

typedef short short8 __attribute__((ext_vector_type(8)));
typedef float f32x4 __attribute__((ext_vector_type(4)));
typedef unsigned long long u64;

__device__ inline uint32_t f2bf1(float x) {
    union { float f; uint32_t u; } v; v.f = x;
    return (v.u + 0x7FFFu + ((v.u >> 16) & 1u)) >> 16;
}
__device__ inline uint32_t pack2(float a, float b) {
    return f2bf1(a) | (f2bf1(b) << 16);
}
__device__ inline float bl(uint32_t x) {
    union { uint32_t u; float f; } v; v.u = x << 16; return v.f;
}
__device__ inline float bh(uint32_t x) {
    union { uint32_t u; float f; } v; v.u = x & 0xFFFF0000u; return v.f;
}
// packed sort key: high32 = monotone float bits, low32 = ~j (bigger = better)
__device__ inline u64 mkkey(float v, int j) {
    union { float f; uint32_t u; } c; c.f = v;
    uint32_t b = c.u;
    uint32_t k = (b & 0x80000000u) ? ~b : (b | 0x80000000u);
    return ((u64)k << 32) | (uint32_t)(~j);
}
__device__ inline u64 umax64(u64 a, u64 b) { return a > b ? a : b; }
__device__ inline u64 shfl_xor_u64(u64 v, int m) {
    int lo = __shfl_xor((int)(uint32_t)v, m, 64);
    int hi = __shfl_xor((int)(v >> 32), m, 64);
    return ((u64)(uint32_t)hi << 32) | (uint32_t)lo;
}
__device__ inline void ins6u(u64 k, u64* lv) {
    if (k > lv[5]) {
        int q = 5;
        while (q > 0 && k > lv[q - 1]) { lv[q] = lv[q - 1]; q--; }
        lv[q] = k;
    }
}
// 256-thread LDS tree merge of per-thread sorted-desc 6-tuples -> sv[0..5]
__device__ inline void tree6u(u64* sv, int t, const u64* lv) {
#pragma unroll
    for (int r = 0; r < 6; r++) sv[t * 6 + r] = lv[r];
    __syncthreads();
    for (int s = 128; s > 0; s >>= 1) {
        if (t < s) {
            u64 av[6], bv[6], rv[6];
#pragma unroll
            for (int r = 0; r < 6; r++) { av[r] = sv[t * 6 + r]; bv[r] = sv[(t + s) * 6 + r]; }
            int x = 0, y = 0;
#pragma unroll
            for (int o = 0; o < 6; o++) {
                bool pk = av[x] > bv[y];
                rv[o] = pk ? av[x] : bv[y];
                x += pk; y += !pk;
            }
#pragma unroll
            for (int r = 0; r < 6; r++) sv[t * 6 + r] = rv[r];
        }
        __syncthreads();
    }
}
// async 16B/lane global->LDS: gptr per-lane, lptr wave-uniform
__device__ inline void async16(const void* g, void* l) {
    __builtin_amdgcn_global_load_lds(
        (const __attribute__((address_space(1))) unsigned int*)g,
        (__attribute__((address_space(3))) unsigned int*)l, 16, 0, 0);
}
// swizzled tiled offset (elements): 128-row x 64-col tile, row r, 8-el chunk ch
__device__ inline size_t sw_off(int tile, int r, int ch) {
    return (size_t)tile * 8192 + r * 64 + ((ch ^ (r & 7)) * 8);
}

// Kernel 1: fused row L2-normalize (-> fnb plain + fnb2 swizzled) + softmax + repl init
__global__ void norm_softmax_kernel(const float* __restrict__ feat,
                                    const float* __restrict__ pred,
                                    unsigned short* __restrict__ fnb,
                                    unsigned short* __restrict__ fnb2,
                                    float* __restrict__ p,
                                    int* __restrict__ repl) {
    int b = blockIdx.x, t = threadIdx.x;
    int gi = b * 256 + t;
    if (gi < NPAD) repl[gi] = -1;
    __shared__ float red[256];
    float x0 = feat[b * DD + t];
    float x1 = feat[b * DD + t + 256];
    red[t] = x0 * x0 + x1 * x1;
    __syncthreads();
    for (int s = 128; s > 0; s >>= 1) {
        if (t < s) red[t] += red[t + s];
        __syncthreads();
    }
    float inv = 1.0f / fmaxf(sqrtf(red[0]), EPSN);
    if (t < 64) {
        const f32x4* src = (const f32x4*)(feat + b * DD + t * 8);
        f32x4 f0 = src[0], f1 = src[1];
        uint4 u = make_uint4(pack2(f0[0] * inv, f0[1] * inv),
                             pack2(f0[2] * inv, f0[3] * inv),
                             pack2(f1[0] * inv, f1[1] * inv),
                             pack2(f1[2] * inv, f1[3] * inv));
        *(uint4*)(fnb + b * DD + t * 8) = u;
        int mtile = b >> 7, r = b & 127, kt = t >> 3, ch = t & 7;
        *(uint4*)(fnb2 + sw_off(mtile * 8 + kt, r, ch)) = u;
    }
    __syncthreads();
    float y0 = (t < CC) ? pred[b * CC + t] : -3.0e38f;
    float y1 = (t + 256 < CC) ? pred[b * CC + t + 256] : -3.0e38f;
    red[t] = fmaxf(y0, y1);
    __syncthreads();
    for (int s = 128; s > 0; s >>= 1) {
        if (t < s) red[t] = fmaxf(red[t], red[t + s]);
        __syncthreads();
    }
    float M = red[0];
    __syncthreads();
    float e0 = (t < CC) ? expf(y0 - M) : 0.f;
    float e1 = (t + 256 < CC) ? expf(y1 - M) : 0.f;
    red[t] = e0 + e1;
    __syncthreads();
    for (int s = 128; s > 0; s >>= 1) {
        if (t < s) red[t] += red[t + s];
        __syncthreads();
    }
    float si = 1.0f / red[0];
    if (t < CC) p[b * CC + t] = e0 * si;
    if (t + 256 < CC) p[b * CC + t + 256] = e1 * si;
}

// Kernel 2: zero out; last-write-wins scatter repl[trg[b]] = b
__global__ void winner_kernel(const int* __restrict__ trg, int* __restrict__ repl,
                              float* __restrict__ out) {
    int t = threadIdx.x;
    __shared__ int st[BB];
    if (t == 0) out[0] = 0.f;
    st[t] = trg[t];
    __syncthreads();
    int mv = st[t];
    int w = 1;
    for (int b2 = t + 1; b2 < BB; b2++)
        if (st[b2] == mv) w = 0;
    if (w) repl[mv] = t;
}

// Kernel 3: 128x64x512 bf16 MFMA GEMM (R2 geometry) with a counted-vmcnt
// software pipeline (guide T3+T4+T14):
//   - A double-buffered via async16 from pre-swizzled fnb2 (2x16KB).
//   - B reg-staged DEPTH-3 (bank f32 -> regs, 3 static sets), converted to
//     bf16 and ds_written LATE (after MFMA), one K-tile ahead.
//   - per K-step: lgkmcnt(0) + vmcnt(4) + RAW s_barrier -- the just-issued
//     B[kt+3] loads STAY IN FLIGHT across the barrier (no vmcnt(0) drain;
//     that drain was R2's 75% duty-cycle loss).
//   - empty asm "memory" fences pin VMEM issue order (A | bank | fnb) so the
//     manual counts are valid in every wave; bank loads are unconditional
//     (OOB rows clamp to NBANK-1, data discarded) so queue shape is uniform.
// Hang-audit (R5): 8 uniform s_barriers/wave, no divergent barrier path;
// s_waitcnt cannot deadlock; all global/LDS offsets bounds-checked.
__global__ __launch_bounds__(256, 3) void gemm_topk_kernel(
        const unsigned short* __restrict__ fnb2, const float* __restrict__ bank,
        const unsigned short* __restrict__ fnb, const int* __restrict__ repl,
        u64* __restrict__ cand) {
    // A dbuf: 2 x 16KB at 0; B dbuf: 2 x 8KB at 32768
    __shared__ __align__(16) char smem[49152];

    int t = threadIdx.x;
    int bid = blockIdx.x;
    int ntb = bid >> 1;            // 0..781 col tile
    int rh  = bid & 1;             // row half
    int j0 = ntb * 64;
    int w = t >> 6, lane = t & 63, quad = lane >> 4, l16 = lane & 15;

    int br = t >> 2, cq = t & 3;   // B staging role: 4 threads per bank row
    int bj = j0 + br;
    int rpv = (j0 + lane < NBANK) ? repl[j0 + lane] : -2;
    int hasP = __any(rpv >= 0);    // wave-uniform patch flag
    int rp = __shfl(rpv, br);      // this thread's row status
    int bjc = (bj < NBANK) ? bj : (NBANK - 1);   // clamped (uniform queue shape)

    const char* fnb2b = (const char*)fnb2;
    const f32x4* bsrc = (const f32x4*)(bank + (size_t)bjc * DD);
    const uint4* psrc = (const uint4*)(fnb + (size_t)((rp >= 0) ? rp : 0) * DD);

    f32x4 pf[3][4];                // depth-3 B prefetch (static idx via unroll)
    uint4 pu0, pu1;                // patch row data (depth-1, L2-fast)

    f32x4 acc[2][4];
#pragma unroll
    for (int mt = 0; mt < 2; mt++)
#pragma unroll
        for (int nt = 0; nt < 4; nt++)
            acc[mt][nt] = (f32x4){0.f, 0.f, 0.f, 0.f};

    // ---------------- prologue ----------------
    {   // A[0] -> Abuf0
        const char* asrc = fnb2b + (size_t)(rh * 8 + 0) * 16384 + w * 4096;
        char* adst = smem + w * 4096;
#pragma unroll
        for (int u = 0; u < 4; u++)
            async16(asrc + u * 1024 + lane * 16, adst + u * 1024);
    }
    asm volatile("" ::: "memory");
    // B tiles 0,1,2 -> reg sets 0,1,2 (unconditional, clamped row)
#pragma unroll
    for (int s = 0; s < 3; s++)
#pragma unroll
        for (int i = 0; i < 4; i++)
            pf[s][i] = bsrc[s * 16 + cq * 4 + i];
    asm volatile("" ::: "memory");
    if (hasP && rp >= 0) { pu0 = psrc[cq * 2]; pu1 = psrc[cq * 2 + 1]; }
    asm volatile("" ::: "memory");
    {   // convert/write tile 0 -> Bbuf0
        uint4 b0, b1;
        if (rp >= 0)      { b0 = pu0; b1 = pu1; }
        else if (rp == -1) {
            b0 = make_uint4(pack2(pf[0][0][0], pf[0][0][1]), pack2(pf[0][0][2], pf[0][0][3]),
                            pack2(pf[0][1][0], pf[0][1][1]), pack2(pf[0][1][2], pf[0][1][3]));
            b1 = make_uint4(pack2(pf[0][2][0], pf[0][2][1]), pack2(pf[0][2][2], pf[0][2][3]),
                            pack2(pf[0][3][0], pf[0][3][1]), pack2(pf[0][3][2], pf[0][3][3]));
        } else { b0 = make_uint4(0, 0, 0, 0); b1 = make_uint4(0, 0, 0, 0); }
        unsigned short* Bn = (unsigned short*)(smem + 32768);
        int c0 = cq * 2;
        *(uint4*)(Bn + br * 64 + ((c0 ^ (br & 7)) * 8)) = b0;
        *(uint4*)(Bn + br * 64 + (((c0 + 1) ^ (br & 7)) * 8)) = b1;
    }
    asm volatile("s_waitcnt lgkmcnt(0)" ::: "memory");
    asm volatile("s_waitcnt vmcnt(12)" ::: "memory");   // A[0]+B[0] done; B[1],B[2] in flight
    __builtin_amdgcn_s_barrier();
    asm volatile("" ::: "memory");

    // ---------------- pipelined main loop ----------------
#pragma unroll
    for (int kt = 0; kt < 8; kt++) {
        if (kt < 7) {   // issue A[kt+1] -> Abuf[(kt+1)&1]
            const char* asrc = fnb2b + (size_t)(rh * 8 + kt + 1) * 16384 + w * 4096;
            char* adst = smem + ((kt + 1) & 1) * 16384 + w * 4096;
#pragma unroll
            for (int u = 0; u < 4; u++)
                async16(asrc + u * 1024 + lane * 16, adst + u * 1024);
        }
        asm volatile("" ::: "memory");
        if (kt + 3 < 8) {   // issue B[kt+3] -> set (kt+3)%3 (unconditional)
#pragma unroll
            for (int i = 0; i < 4; i++)
                pf[(kt + 3) % 3][i] = bsrc[(kt + 3) * 16 + cq * 4 + i];
        }
        asm volatile("" ::: "memory");
        if (kt < 7 && hasP && rp >= 0) {   // patch row data for tile kt+1
            pu0 = psrc[(kt + 1) * 4 + cq * 2];
            pu1 = psrc[(kt + 1) * 4 + cq * 2 + 1];
        }
        asm volatile("" ::: "memory");

        // MFMA kt from buf[kt&1]
        const unsigned short* As = (const unsigned short*)(smem + (kt & 1) * 16384);
        const unsigned short* Bs = (const unsigned short*)(smem + 32768 + (kt & 1) * 8192);
#pragma unroll
        for (int ks = 0; ks < 2; ks++) {
            int swz = ((ks * 4 + quad) ^ (l16 & 7)) * 8;
            short8 af[2], bf[4];
#pragma unroll
            for (int mt = 0; mt < 2; mt++)
                af[mt] = *(const short8*)(As + (w * 32 + mt * 16 + l16) * 64 + swz);
#pragma unroll
            for (int nt = 0; nt < 4; nt++)
                bf[nt] = *(const short8*)(Bs + (nt * 16 + l16) * 64 + swz);
#pragma unroll
            for (int mt = 0; mt < 2; mt++)
#pragma unroll
                for (int nt = 0; nt < 4; nt++)
                    acc[mt][nt] = __builtin_amdgcn_mfma_f32_16x16x32_bf16(
                        af[mt], bf[nt], acc[mt][nt], 0, 0, 0);
        }

        if (kt < 7) {   // convert/write tile kt+1 -> Bbuf[(kt+1)&1] (write-late)
            uint4 b0, b1;
            if (rp >= 0)      { b0 = pu0; b1 = pu1; }
            else if (rp == -1) {
                const f32x4* q = pf[(kt + 1) % 3];
                b0 = make_uint4(pack2(q[0][0], q[0][1]), pack2(q[0][2], q[0][3]),
                                pack2(q[1][0], q[1][1]), pack2(q[1][2], q[1][3]));
                b1 = make_uint4(pack2(q[2][0], q[2][1]), pack2(q[2][2], q[2][3]),
                                pack2(q[3][0], q[3][1]), pack2(q[3][2], q[3][3]));
            } else { b0 = make_uint4(0, 0, 0, 0); b1 = make_uint4(0, 0, 0, 0); }
            unsigned short* Bn = (unsigned short*)(smem + 32768 + ((kt + 1) & 1) * 8192);
            int c0 = cq * 2;
            *(uint4*)(Bn + br * 64 + ((c0 ^ (br & 7)) * 8)) = b0;
            *(uint4*)(Bn + br * 64 + (((c0 + 1) ^ (br & 7)) * 8)) = b1;

            asm volatile("s_waitcnt lgkmcnt(0)" ::: "memory");
            if (kt <= 4) {
                // leave B[kt+3] (4 newest) in flight across the barrier
                asm volatile("s_waitcnt vmcnt(4)" ::: "memory");
            } else {
                asm volatile("s_waitcnt vmcnt(0)" ::: "memory");
            }
            __builtin_amdgcn_s_barrier();
            asm volatile("" ::: "memory");
        }
    }

    // ---- branchless epilogue: top-2 packed keys per (row, 64 cols) ----
    bool maskPad[4];
#pragma unroll
    for (int nt = 0; nt < 4; nt++)
        maskPad[nt] = (ntb == NHALF - 1) && ((j0 + nt * 16 + l16) >= NBANK);

#pragma unroll
    for (int mt = 0; mt < 2; mt++)
#pragma unroll
        for (int r2 = 0; r2 < 4; r2++) {
            u64 k[4];
#pragma unroll
            for (int nt = 0; nt < 4; nt++) {
                int j = j0 + nt * 16 + l16;
                k[nt] = maskPad[nt] ? 0ull : mkkey(acc[mt][nt][r2], j);
            }
            u64 m = umax64(umax64(k[0], k[1]), umax64(k[2], k[3]));
#pragma unroll
            for (int off = 1; off < 16; off <<= 1)
                m = umax64(m, shfl_xor_u64(m, off));
            u64 top1 = m;
#pragma unroll
            for (int nt = 0; nt < 4; nt++) k[nt] = (k[nt] == top1) ? 0ull : k[nt];
            m = umax64(umax64(k[0], k[1]), umax64(k[2], k[3]));
#pragma unroll
            for (int off = 1; off < 16; off <<= 1)
                m = umax64(m, shfl_xor_u64(m, off));
            if (l16 == 0) {
                int gi = rh * 128 + w * 32 + mt * 16 + quad * 4 + r2;
                u64* cp = cand + (size_t)gi * CSLOTS + ntb * 2;
                cp[0] = top1; cp[1] = m;
            }
        }
}

// Kernel 4: fused merge + KL (blocks 0..255) and neg_pred (blocks 256..600).
__global__ __launch_bounds__(256) void mergekl_kernel(
        const u64* __restrict__ cand, const unsigned short* __restrict__ fnb,
        const float* __restrict__ bank, const int* __restrict__ repl,
        const float* __restrict__ p, const float* __restrict__ sbank,
        const int* __restrict__ trg, float* __restrict__ out) {
    int bid = blockIdx.x, t = threadIdx.x;
    __shared__ float red[256];
    if (bid >= BB) {
        __shared__ float aux[256];
        int c = bid - BB;
        float v = p[t * CC + c];
        red[t] = v;
        aux[t] = v * v;
        __syncthreads();
        for (int s = 128; s > 0; s >>= 1) {
            if (t < s) { red[t] += red[t + s]; aux[t] += aux[t + s]; }
            __syncthreads();
        }
        if (t == 0) atomicAdd(out, ALPHAC * (red[0] * red[0] - aux[0]) * (1.0f / BB));
        return;
    }
    int i = bid;
    __shared__ u64 sv[1536];
    __shared__ uint32_t fm[25];
    __shared__ int fl[128];
    __shared__ int nf;
    __shared__ float a[512];
    const u64* cr = cand + (size_t)i * CSLOTS;

    u64 lv[6] = {0, 0, 0, 0, 0, 0};
    for (int q = t; q < CSLOTS; q += 256) ins6u(cr[q], lv);
    if (t < 25) fm[t] = 0;
    if (t == 0) nf = 0;
    tree6u(sv, t, lv);
    u64 M6 = sv[5];
    __syncthreads();
    for (int h = t; h < NHALF; h += 256) {
        if (cr[h * 2 + 1] >= M6) {
            int s = atomicAdd(&nf, 1);
            if (s < 128) fl[s] = h;
            atomicOr(&fm[h >> 5], 1u << (h & 31));
        }
    }
    __syncthreads();
    if (nf > 0) {   // exact fallback — rare
        uint32_t wrd = ((const uint32_t*)(fnb + (size_t)i * DD))[t];
        a[2 * t] = bl(wrd);
        a[2 * t + 1] = bh(wrd);
        __syncthreads();
        u64 l2[6] = {0, 0, 0, 0, 0, 0};
        for (int q = t; q < CSLOTS; q += 256) {
            int h = q >> 1;
            if (!((fm[h >> 5] >> (h & 31)) & 1u)) ins6u(cr[q], l2);
        }
        int nfl = nf < 128 ? nf : 128;
        for (int s = 0; s < nfl; s++) {
            int h = fl[s];
            if (t < 64) {
                int j = h * 64 + t;
                if (j < NBANK) {
                    int rp = repl[j];
                    float dot = 0.f;
                    if (rp >= 0) {
                        const uint32_t* rw = (const uint32_t*)(fnb + (size_t)rp * DD);
                        for (int kk = 0; kk < 256; kk++) {
                            uint32_t u = rw[kk];
                            dot += bl(u) * a[2 * kk] + bh(u) * a[2 * kk + 1];
                        }
                    } else {
                        const float* rw = bank + (size_t)j * DD;
                        for (int kk = 0; kk < DD; kk++)
                            dot += bl(f2bf1(rw[kk])) * a[kk];
                    }
                    ins6u(mkkey(dot, j), l2);
                }
            }
        }
        __syncthreads();
        tree6u(sv, t, l2);
    }
    __shared__ int st[BB];
    __shared__ int sj[KNEI], sb2[KNEI];
    st[t] = trg[t];
    if (t < KNEI) {
        sj[t] = (int)(~(uint32_t)(sv[t + 1] & 0xFFFFFFFFull));
        sb2[t] = -1;
    }
    __syncthreads();
#pragma unroll
    for (int k = 0; k < KNEI; k++)
        if (st[t] == sj[k]) atomicMax(&sb2[k], t);
    __syncthreads();
    float local = 0.f;
    for (int k = 0; k < KNEI; k++) {
        int j = sj[k], src = sb2[k];
        const float* srow = (src >= 0) ? (p + src * CC) : (sbank + (size_t)j * CC);
        for (int c = t; c < CC; c += 256) {
            float s = srow[c];
            local += s * (logf(s) - p[i * CC + c]);
        }
    }
    red[t] = local;
    __syncthreads();
    for (int s = 128; s > 0; s >>= 1) {
        if (t < s) red[t] += red[t + s];
        __syncthreads();
    }
    if (t == 0) atomicAdd(out, red[0] * (1.0f / BB));
}

extern "C" void kernel_launch(void* const* d_in, const int* in_sizes, int n_in,
                              void* d_out, int out_size, void* d_ws, size_t ws_size,
                              hipStream_t stream) {
    const float* feat  = (const float*)d_in[0];
    const float* pred  = (const float*)d_in[1];
    const float* bank  = (const float*)d_in[2];
    const float* sbank = (const float*)d_in[3];
    const int*   trg   = (const int*)d_in[4];
    float* out = (float*)d_out;

    char* ws = (char*)d_ws;
    unsigned short* fnb2 = (unsigned short*)ws;              //   262,144 B
    unsigned short* fnb  = (unsigned short*)(ws + 262144);   //   262,144 B
    float*          p    = (float*)(ws + 524288);            //   353,280 B
    int*            repl = (int*)(ws + 877568);              //   200,192 B
    u64*            cand = (u64*)(ws + 1077760);             // 3,203,072 B

    norm_softmax_kernel<<<BB, 256, 0, stream>>>(feat, pred, fnb, fnb2, p, repl);
    winner_kernel<<<1, 256, 0, stream>>>(trg, repl, out);
    gemm_topk_kernel<<<NHALF * 2, 256, 0, stream>>>(fnb2, bank, fnb, repl, cand);
    mergekl_kernel<<<BB + CC, 256, 0, stream>>>(cand, fnb, bank, repl, p, sbank, trg, out);
}

// Round 7
// 264.022 us; speedup vs baseline: 1.1312x; 1.0244x over previous
//
#include <hip/hip_runtime.h>
#include <cstdint>

#define BB 256
#define DD 512
#define CC 345
#define NBANK 50000
#define KNEI 5
#define ALPHAC 1.0f
#define EPSN 1e-12f
#define NHALF 782           // 64-col tiles
#define CSLOTS (NHALF * 2)  // 2 keys per tile -> 1564 u64 per row

typedef short short8 __attribute__((ext_vector_type(8)));
typedef float f32x4 __attribute__((ext_vector_type(4)));
typedef unsigned long long u64;

__device__ inline uint32_t f2bf1(float x) {
    union { float f; uint32_t u; } v; v.f = x;
    return (v.u + 0x7FFFu + ((v.u >> 16) & 1u)) >> 16;
}
__device__ inline uint32_t pack2(float a, float b) {
    return f2bf1(a) | (f2bf1(b) << 16);
}
__device__ inline float bl(uint32_t x) {
    union { uint32_t u; float f; } v; v.u = x << 16; return v.f;
}
__device__ inline float bh(uint32_t x) {
    union { uint32_t u; float f; } v; v.u = x & 0xFFFF0000u; return v.f;
}
// packed sort key: high32 = monotone float bits, low32 = ~j (bigger = better)
__device__ inline u64 mkkey(float v, int j) {
    union { float f; uint32_t u; } c; c.f = v;
    uint32_t b = c.u;
    uint32_t k = (b & 0x80000000u) ? ~b : (b | 0x80000000u);
    return ((u64)k << 32) | (uint32_t)(~j);
}
__device__ inline u64 umax64(u64 a, u64 b) { return a > b ? a : b; }
__device__ inline u64 shfl_xor_u64(u64 v, int m) {
    int lo = __shfl_xor((int)(uint32_t)v, m, 64);
    int hi = __shfl_xor((int)(v >> 32), m, 64);
    return ((u64)(uint32_t)hi << 32) | (uint32_t)lo;
}
__device__ inline void ins6u(u64 k, u64* lv) {
    if (k > lv[5]) {
        int q = 5;
        while (q > 0 && k > lv[q - 1]) { lv[q] = lv[q - 1]; q--; }
        lv[q] = k;
    }
}
// 256-thread LDS tree merge of per-thread sorted-desc 6-tuples -> sv[0..5]
__device__ inline void tree6u(u64* sv, int t, const u64* lv) {
#pragma unroll
    for (int r = 0; r < 6; r++) sv[t * 6 + r] = lv[r];
    __syncthreads();
    for (int s = 128; s > 0; s >>= 1) {
        if (t < s) {
            u64 av[6], bv[6], rv[6];
#pragma unroll
            for (int r = 0; r < 6; r++) { av[r] = sv[t * 6 + r]; bv[r] = sv[(t + s) * 6 + r]; }
            int x = 0, y = 0;
#pragma unroll
            for (int o = 0; o < 6; o++) {
                bool pk = av[x] > bv[y];
                rv[o] = pk ? av[x] : bv[y];
                x += pk; y += !pk;
            }
#pragma unroll
            for (int r = 0; r < 6; r++) sv[t * 6 + r] = rv[r];
        }
        __syncthreads();
    }
}
// async 16B/lane global->LDS: gptr per-lane, lptr wave-uniform
__device__ inline void async16(const void* g, void* l) {
    __builtin_amdgcn_global_load_lds(
        (const __attribute__((address_space(1))) unsigned int*)g,
        (__attribute__((address_space(3))) unsigned int*)l, 16, 0, 0);
}
// swizzled tiled offset (elements): 128-row x 64-col tile, row r, 8-el chunk ch
__device__ inline size_t sw_off(int tile, int r, int ch) {
    return (size_t)tile * 8192 + r * 64 + ((ch ^ (r & 7)) * 8);
}

// Kernel 1: fused row L2-normalize (-> fnb plain + fnb2 swizzled) + softmax
// + out zero (block 0). repl array ELIMINATED (winner recomputed in consumers).
__global__ void norm_softmax_kernel(const float* __restrict__ feat,
                                    const float* __restrict__ pred,
                                    unsigned short* __restrict__ fnb,
                                    unsigned short* __restrict__ fnb2,
                                    float* __restrict__ p,
                                    float* __restrict__ out) {
    int b = blockIdx.x, t = threadIdx.x;
    if (b == 0 && t == 0) out[0] = 0.f;
    __shared__ float red[256];
    float x0 = feat[b * DD + t];
    float x1 = feat[b * DD + t + 256];
    red[t] = x0 * x0 + x1 * x1;
    __syncthreads();
    for (int s = 128; s > 0; s >>= 1) {
        if (t < s) red[t] += red[t + s];
        __syncthreads();
    }
    float inv = 1.0f / fmaxf(sqrtf(red[0]), EPSN);
    if (t < 64) {
        const f32x4* src = (const f32x4*)(feat + b * DD + t * 8);
        f32x4 f0 = src[0], f1 = src[1];
        uint4 u = make_uint4(pack2(f0[0] * inv, f0[1] * inv),
                             pack2(f0[2] * inv, f0[3] * inv),
                             pack2(f1[0] * inv, f1[1] * inv),
                             pack2(f1[2] * inv, f1[3] * inv));
        *(uint4*)(fnb + b * DD + t * 8) = u;
        int mtile = b >> 7, r = b & 127, kt = t >> 3, ch = t & 7;
        *(uint4*)(fnb2 + sw_off(mtile * 8 + kt, r, ch)) = u;
    }
    __syncthreads();
    float y0 = (t < CC) ? pred[b * CC + t] : -3.0e38f;
    float y1 = (t + 256 < CC) ? pred[b * CC + t + 256] : -3.0e38f;
    red[t] = fmaxf(y0, y1);
    __syncthreads();
    for (int s = 128; s > 0; s >>= 1) {
        if (t < s) red[t] = fmaxf(red[t], red[t + s]);
        __syncthreads();
    }
    float M = red[0];
    __syncthreads();
    float e0 = (t < CC) ? expf(y0 - M) : 0.f;
    float e1 = (t + 256 < CC) ? expf(y1 - M) : 0.f;
    red[t] = e0 + e1;
    __syncthreads();
    for (int s = 128; s > 0; s >>= 1) {
        if (t < s) red[t] += red[t + s];
        __syncthreads();
    }
    float si = 1.0f / red[0];
    if (t < CC) p[b * CC + t] = e0 * si;
    if (t + 256 < CC) p[b * CC + t + 256] = e1 * si;
}

// Kernel 2: 128x64x512 bf16 MFMA GEMM — EXACT R2 schedule (measured 61us,
// occ 38%, 1.8 TB/s, 0 bank conflicts). Only change: rp comes from an
// in-block LDS atomicMax winner scatter over trg (last-write-wins), which
// replaces the repl array + its init and scatter kernels.
__global__ __launch_bounds__(256) void gemm_topk_kernel(
        const unsigned short* __restrict__ fnb2, const float* __restrict__ bank,
        const unsigned short* __restrict__ fnb, const int* __restrict__ trg,
        u64* __restrict__ cand) {
    __shared__ __align__(16) char smem[24576];
    unsigned short* As = (unsigned short*)smem;            // [128][64] 16 KB
    unsigned short* Bs = (unsigned short*)(smem + 16384);  // [64][64]   8 KB
    __shared__ int rpl[64];

    int t = threadIdx.x;
    int bid = blockIdx.x;
    int ntb = bid >> 1;            // 0..781 col tile
    int rh  = bid & 1;             // row half: rows rh*128 .. rh*128+127
    int j0 = ntb * 64;
    int w = t >> 6, lane = t & 63, quad = lane >> 4, l16 = lane & 15;

    // ---- in-block winner: rpl[r] = max b with trg[b] == j0+r, else -1 ----
    if (t < 64) rpl[t] = -1;
    int tv = trg[t];
    __syncthreads();
    {
        int d = tv - j0;
        if (d >= 0 && d < 64) atomicMax(&rpl[d], t);
    }
    __syncthreads();

    // B staging role: 4 threads per bank row, 16 floats each
    int br = t >> 2, cq = t & 3;
    int bj = j0 + br;
    int rp = (bj < NBANK) ? rpl[br] : -2;   // -2 OOB, -1 bank row, >=0 fnb row

    f32x4 acc[2][4];
#pragma unroll
    for (int mt = 0; mt < 2; mt++)
#pragma unroll
        for (int nt = 0; nt < 4; nt++)
            acc[mt][nt] = (f32x4){0.f, 0.f, 0.f, 0.f};

    const char* fnb2b = (const char*)fnb2;

    for (int kt = 0; kt < 8; kt++) {
        // A: async16 from swizzled fnb2 tile (rh*8+kt); wave w copies 4 KB
        const char* asrc = fnb2b + (size_t)((rh * 8 + kt) * 16384 + w * 4096);
        char* adst = smem + w * 4096;
#pragma unroll
        for (int u = 0; u < 4; u++)
            async16(asrc + u * 1024 + lane * 16, adst + u * 1024);
        // B: f32 bank -> registers -> bf16 -> swizzled LDS (winner-patched)
        {
            uint4 b0, b1;
            if (rp >= 0) {
                const uint4* s = (const uint4*)(fnb + (size_t)rp * DD + kt * 64 + cq * 16);
                b0 = s[0]; b1 = s[1];
            } else if (rp == -1) {
                const f32x4* s = (const f32x4*)(bank + (size_t)bj * DD + kt * 64 + cq * 16);
                f32x4 f0 = s[0], f1 = s[1], f2 = s[2], f3 = s[3];
                b0 = make_uint4(pack2(f0[0], f0[1]), pack2(f0[2], f0[3]),
                                pack2(f1[0], f1[1]), pack2(f1[2], f1[3]));
                b1 = make_uint4(pack2(f2[0], f2[1]), pack2(f2[2], f2[3]),
                                pack2(f3[0], f3[1]), pack2(f3[2], f3[3]));
            } else {
                b0 = make_uint4(0, 0, 0, 0);
                b1 = make_uint4(0, 0, 0, 0);
            }
            int c0 = cq * 2;
            *(uint4*)(Bs + br * 64 + ((c0 ^ (br & 7)) * 8)) = b0;
            *(uint4*)(Bs + br * 64 + (((c0 + 1) ^ (br & 7)) * 8)) = b1;
        }
        __syncthreads();
#pragma unroll
        for (int ks = 0; ks < 2; ks++) {
            int swz = ((ks * 4 + quad) ^ (l16 & 7)) * 8;
            short8 af[2], bf[4];
#pragma unroll
            for (int mt = 0; mt < 2; mt++)
                af[mt] = *(const short8*)(As + (w * 32 + mt * 16 + l16) * 64 + swz);
#pragma unroll
            for (int nt = 0; nt < 4; nt++)
                bf[nt] = *(const short8*)(Bs + (nt * 16 + l16) * 64 + swz);
#pragma unroll
            for (int mt = 0; mt < 2; mt++)
#pragma unroll
                for (int nt = 0; nt < 4; nt++)
                    acc[mt][nt] = __builtin_amdgcn_mfma_f32_16x16x32_bf16(
                        af[mt], bf[nt], acc[mt][nt], 0, 0, 0);
        }
        __syncthreads();
    }

    // Branchless epilogue: top-2 packed keys per (row, this block's 64 cols)
    bool maskPad[4];
#pragma unroll
    for (int nt = 0; nt < 4; nt++)
        maskPad[nt] = (ntb == NHALF - 1) && ((j0 + nt * 16 + l16) >= NBANK);

#pragma unroll
    for (int mt = 0; mt < 2; mt++)
#pragma unroll
        for (int r2 = 0; r2 < 4; r2++) {
            u64 k[4];
#pragma unroll
            for (int nt = 0; nt < 4; nt++) {
                int j = j0 + nt * 16 + l16;
                k[nt] = maskPad[nt] ? 0ull : mkkey(acc[mt][nt][r2], j);
            }
            u64 m = umax64(umax64(k[0], k[1]), umax64(k[2], k[3]));
#pragma unroll
            for (int off = 1; off < 16; off <<= 1)
                m = umax64(m, shfl_xor_u64(m, off));
            u64 top1 = m;
#pragma unroll
            for (int nt = 0; nt < 4; nt++) k[nt] = (k[nt] == top1) ? 0ull : k[nt];
            m = umax64(umax64(k[0], k[1]), umax64(k[2], k[3]));
#pragma unroll
            for (int off = 1; off < 16; off <<= 1)
                m = umax64(m, shfl_xor_u64(m, off));
            if (l16 == 0) {
                int gi = rh * 128 + w * 32 + mt * 16 + quad * 4 + r2;
                u64* cp = cand + (size_t)gi * CSLOTS + ntb * 2;
                cp[0] = top1; cp[1] = m;
            }
        }
}

// Kernel 3: fused merge + KL (blocks 0..255) and neg_pred (blocks 256..600).
// repl replaced by an in-LDS trg scan (last-write-wins) in the rare fallback.
__global__ __launch_bounds__(256) void mergekl_kernel(
        const u64* __restrict__ cand, const unsigned short* __restrict__ fnb,
        const float* __restrict__ bank, const int* __restrict__ trg,
        const float* __restrict__ p, const float* __restrict__ sbank,
        float* __restrict__ out) {
    int bid = blockIdx.x, t = threadIdx.x;
    __shared__ float red[256];
    if (bid >= BB) {
        // ---- neg_pred column block ----
        __shared__ float aux[256];
        int c = bid - BB;
        float v = p[t * CC + c];
        red[t] = v;
        aux[t] = v * v;
        __syncthreads();
        for (int s = 128; s > 0; s >>= 1) {
            if (t < s) { red[t] += red[t + s]; aux[t] += aux[t + s]; }
            __syncthreads();
        }
        if (t == 0) atomicAdd(out, ALPHAC * (red[0] * red[0] - aux[0]) * (1.0f / BB));
        return;
    }
    // ---- merge part ----
    int i = bid;
    __shared__ u64 sv[1536];
    __shared__ uint32_t fm[25];
    __shared__ int fl[128];
    __shared__ int nf;
    __shared__ float a[512];
    __shared__ int st[BB];
    const u64* cr = cand + (size_t)i * CSLOTS;

    st[t] = trg[t];
    u64 lv[6] = {0, 0, 0, 0, 0, 0};
    for (int q = t; q < CSLOTS; q += 256) ins6u(cr[q], lv);
    if (t < 25) fm[t] = 0;
    if (t == 0) nf = 0;
    tree6u(sv, t, lv);
    u64 M6 = sv[5];
    __syncthreads();
    for (int h = t; h < NHALF; h += 256) {
        if (cr[h * 2 + 1] >= M6) {
            int s = atomicAdd(&nf, 1);
            if (s < 128) fl[s] = h;
            atomicOr(&fm[h >> 5], 1u << (h & 31));
        }
    }
    __syncthreads();
    if (nf > 0) {   // exact fallback — rare
        uint32_t wrd = ((const uint32_t*)(fnb + (size_t)i * DD))[t];
        a[2 * t] = bl(wrd);
        a[2 * t + 1] = bh(wrd);
        __syncthreads();
        u64 l2[6] = {0, 0, 0, 0, 0, 0};
        for (int q = t; q < CSLOTS; q += 256) {    // stored keys, unflagged tiles
            int h = q >> 1;
            if (!((fm[h >> 5] >> (h & 31)) & 1u)) ins6u(cr[q], l2);
        }
        int nfl = nf < 128 ? nf : 128;
        for (int s = 0; s < nfl; s++) {            // full recompute, flagged tiles
            int h = fl[s];
            if (t < 64) {
                int j = h * 64 + t;
                if (j < NBANK) {
                    int rp = -1;                    // last-write-wins winner scan
                    for (int b2 = 0; b2 < BB; b2++)
                        if (st[b2] == j) rp = b2;
                    float dot = 0.f;
                    if (rp >= 0) {
                        const uint32_t* rw = (const uint32_t*)(fnb + (size_t)rp * DD);
                        for (int kk = 0; kk < 256; kk++) {
                            uint32_t u = rw[kk];
                            dot += bl(u) * a[2 * kk] + bh(u) * a[2 * kk + 1];
                        }
                    } else {
                        const float* rw = bank + (size_t)j * DD;
                        for (int kk = 0; kk < DD; kk++)
                            dot += bl(f2bf1(rw[kk])) * a[kk];
                    }
                    ins6u(mkkey(dot, j), l2);
                }
            }
        }
        __syncthreads();
        tree6u(sv, t, l2);
    }
    // ---- KL part: neighbors are sv[1..5] (rank 0 = self) ----
    __shared__ int sj[KNEI], sb2[KNEI];
    if (t < KNEI) {
        sj[t] = (int)(~(uint32_t)(sv[t + 1] & 0xFFFFFFFFull));
        sb2[t] = -1;
    }
    __syncthreads();
    // last-write-wins source: highest b2 with trg[b2] == j
#pragma unroll
    for (int k = 0; k < KNEI; k++)
        if (st[t] == sj[k]) atomicMax(&sb2[k], t);
    __syncthreads();
    float local = 0.f;
    for (int k = 0; k < KNEI; k++) {
        int j = sj[k], src = sb2[k];
        const float* srow = (src >= 0) ? (p + src * CC) : (sbank + (size_t)j * CC);
        for (int c = t; c < CC; c += 256) {
            float s = srow[c];
            local += s * (logf(s) - p[i * CC + c]);
        }
    }
    red[t] = local;
    __syncthreads();
    for (int s = 128; s > 0; s >>= 1) {
        if (t < s) red[t] += red[t + s];
        __syncthreads();
    }
    if (t == 0) atomicAdd(out, red[0] * (1.0f / BB));
}

extern "C" void kernel_launch(void* const* d_in, const int* in_sizes, int n_in,
                              void* d_out, int out_size, void* d_ws, size_t ws_size,
                              hipStream_t stream) {
    const float* feat  = (const float*)d_in[0];
    const float* pred  = (const float*)d_in[1];
    const float* bank  = (const float*)d_in[2];
    const float* sbank = (const float*)d_in[3];
    const int*   trg   = (const int*)d_in[4];
    float* out = (float*)d_out;

    char* ws = (char*)d_ws;
    unsigned short* fnb2 = (unsigned short*)ws;              //   262,144 B
    unsigned short* fnb  = (unsigned short*)(ws + 262144);   //   262,144 B
    float*          p    = (float*)(ws + 524288);            //   353,280 B
    u64*            cand = (u64*)(ws + 877568);              // 3,203,072 B

    norm_softmax_kernel<<<BB, 256, 0, stream>>>(feat, pred, fnb, fnb2, p, out);
    gemm_topk_kernel<<<NHALF * 2, 256, 0, stream>>>(fnb2, bank, fnb, trg, cand);
    mergekl_kernel<<<BB + CC, 256, 0, stream>>>(cand, fnb, bank, trg, p, sbank, out);
}